// Round 1
// baseline (2448.430 us; speedup 1.0000x reference)
//
#include <hip/hip_runtime.h>

#define BB 128
#define TT 2048
#define HH 64
#define GG 192   // 3*H

__device__ __forceinline__ float sigm(float v) {
    return __builtin_amdgcn_rcpf(1.0f + __expf(-v));
}
__device__ __forceinline__ float ftanh(float v) {
    float e = __expf(-2.0f * fabsf(v));
    float r = (1.0f - e) * __builtin_amdgcn_rcpf(1.0f + e);
    return copysignf(r, v);
}

__global__ __launch_bounds__(GG, 1)
void gru_fused(const float* __restrict__ x,
               const float* __restrict__ Wih0, const float* __restrict__ Whh0,
               const float* __restrict__ bih0, const float* __restrict__ bhh0,
               const float* __restrict__ Wih1, const float* __restrict__ Whh1,
               const float* __restrict__ bih1, const float* __restrict__ bhh1,
               const float* __restrict__ fcw, const float* __restrict__ fcb,
               float* __restrict__ out)
{
    const int b = blockIdx.x;
    const int t = threadIdx.x;   // 0..191: gate-row owner

    __shared__ __align__(16) float xs[TT * 2];   // this batch's input, 16 KB
    __shared__ __align__(16) float h1[HH];
    __shared__ __align__(16) float h2[HH];
    __shared__ __align__(16) float hg1[GG];      // W_hh0 · h1 + b_hh0
    __shared__ __align__(16) float xg [GG];      // W_ih1 · h1 + b_ih1
    __shared__ __align__(16) float hg2[GG];      // W_hh1 · h2 + b_hh1

    // --- weights for row t into registers (192 VGPRs; 1 wave/EU => no spill) ---
    float4 w0[16], w1[16], w2[16];
    {
        const float4* p0 = (const float4*)(Whh0 + t * HH);
        const float4* p1 = (const float4*)(Wih1 + t * HH);
        const float4* p2 = (const float4*)(Whh1 + t * HH);
        #pragma unroll
        for (int k = 0; k < 16; ++k) { w0[k] = p0[k]; w1[k] = p1[k]; w2[k] = p2[k]; }
    }
    const float bh0 = bhh0[t], bi1 = bih1[t], bh1 = bhh1[t];

    // --- layer-1 gate-thread constants (threads 0..63) ---
    float wir0=0, wir1=0, wiz0=0, wiz1=0, win0=0, win1=0, bir=0, biz=0, bin=0;
    if (t < HH) {
        wir0 = Wih0[(t         )*2]; wir1 = Wih0[(t         )*2+1];
        wiz0 = Wih0[(HH   + t  )*2]; wiz1 = Wih0[(HH   + t  )*2+1];
        win0 = Wih0[(2*HH + t  )*2]; win1 = Wih0[(2*HH + t  )*2+1];
        bir  = bih0[t]; biz = bih0[HH + t]; bin = bih0[2*HH + t];
    }
    // --- layer-2 gate-thread constants (threads 64..127) ---
    float fcwj = 0.f;
    if (t >= HH && t < 2*HH) fcwj = fcw[t - HH];
    const float fcbv = fcb[0];

    // --- preload x for this batch into LDS ---
    {
        const float4* xp  = (const float4*)(x + (size_t)b * TT * 2);
        float4*       xsp = (float4*)xs;
        for (int i = t; i < TT * 2 / 4; i += GG) xsp[i] = xp[i];
    }
    if (t < HH) { h1[t] = 0.f; h2[t] = 0.f; }
    __syncthreads();

    // Pipelined: iteration i computes layer-1 step i and layer-2 step i-1.
    // Stage A reads only h1[i-1] and h2[i-2] -> all three dots are independent.
    for (int i = 0; i <= TT; ++i) {
        const float4* h14 = (const float4*)h1;
        const float4* h24 = (const float4*)h2;
        float a0 = 0.f, a1 = 0.f, a2 = 0.f;
        float c0 = 0.f, c1 = 0.f, c2 = 0.f;
        #pragma unroll
        for (int k = 0; k < 16; k += 2) {
            float4 ha = h14[k], hb = h14[k + 1];
            float4 ga = h24[k], gb = h24[k + 1];
            a0 += w0[k].x*ha.x + w0[k].y*ha.y + w0[k].z*ha.z + w0[k].w*ha.w;
            c0 += w0[k+1].x*hb.x + w0[k+1].y*hb.y + w0[k+1].z*hb.z + w0[k+1].w*hb.w;
            a1 += w1[k].x*ha.x + w1[k].y*ha.y + w1[k].z*ha.z + w1[k].w*ha.w;
            c1 += w1[k+1].x*hb.x + w1[k+1].y*hb.y + w1[k+1].z*hb.z + w1[k+1].w*hb.w;
            a2 += w2[k].x*ga.x + w2[k].y*ga.y + w2[k].z*ga.z + w2[k].w*ga.w;
            c2 += w2[k+1].x*gb.x + w2[k+1].y*gb.y + w2[k+1].z*gb.z + w2[k+1].w*gb.w;
        }
        hg1[t] = bh0 + a0 + c0;
        xg [t] = bi1 + a1 + c1;
        hg2[t] = bh1 + a2 + c2;
        __syncthreads();

        if (t < HH) {
            if (i < TT) {                       // layer-1 gates, step i (wave 0)
                float x0 = xs[2*i], x1 = xs[2*i + 1];
                float r = sigm (bir + wir0*x0 + wir1*x1 + hg1[t]);
                float z = sigm (biz + wiz0*x0 + wiz1*x1 + hg1[HH + t]);
                float n = ftanh(bin + win0*x0 + win1*x1 + r * hg1[2*HH + t]);
                h1[t] = (1.f - z) * n + z * h1[t];
            }
        } else if (t < 2*HH) {
            if (i > 0) {                        // layer-2 gates, step i-1 (wave 1)
                int j = t - HH;
                float r = sigm (xg[j]        + hg2[j]);
                float z = sigm (xg[HH + j]   + hg2[HH + j]);
                float n = ftanh(xg[2*HH + j] + r * hg2[2*HH + j]);
                float hn = (1.f - z) * n + z * h2[j];
                h2[j] = hn;
                float p = hn * fcwj;            // fc head: 64-dot via wave reduce
                #pragma unroll
                for (int d = 32; d > 0; d >>= 1) p += __shfl_down(p, d, 64);
                if (j == 0) out[(size_t)b * TT + (i - 1)] = p + fcbv;
            }
        }
        __syncthreads();
    }
}

extern "C" void kernel_launch(void* const* d_in, const int* in_sizes, int n_in,
                              void* d_out, int out_size, void* d_ws, size_t ws_size,
                              hipStream_t stream) {
    const float* x    = (const float*)d_in[0];
    const float* Wih0 = (const float*)d_in[1];
    const float* Whh0 = (const float*)d_in[2];
    const float* bih0 = (const float*)d_in[3];
    const float* bhh0 = (const float*)d_in[4];
    const float* Wih1 = (const float*)d_in[5];
    const float* Whh1 = (const float*)d_in[6];
    const float* bih1 = (const float*)d_in[7];
    const float* bhh1 = (const float*)d_in[8];
    const float* fcw  = (const float*)d_in[9];
    const float* fcb  = (const float*)d_in[10];
    float* out = (float*)d_out;

    gru_fused<<<BB, GG, 0, stream>>>(x, Wih0, Whh0, bih0, bhh0,
                                     Wih1, Whh1, bih1, bhh1, fcw, fcb, out);
}

// Round 2
// 1771.507 us; speedup vs baseline: 1.3821x; 1.3821x over previous
//
#include <hip/hip_runtime.h>

#define BB 128
#define TT 2048
#define HH 64

__device__ __forceinline__ float sigm(float v) {
    return __builtin_amdgcn_rcpf(1.0f + __expf(-v));
}
__device__ __forceinline__ float ftanh(float v) {
    float e = __expf(-2.0f * fabsf(v));
    float r = (1.0f - e) * __builtin_amdgcn_rcpf(1.0f + e);
    return copysignf(r, v);
}

// One block per batch. 3 waves:
//   wave0: h1(i)   = GRU1(h1(i-1), x(i))        [hg1 in registers]
//   wave1: xg(i-1) = Wih1*h1(i-1)+bih1          [from LDS h1, parity buffer]
//   wave2: h2(i-2) = GRU2(h2(i-3), xg(i-2))     [hg2 in registers]
// Single barrier per iteration: every wave reads only LDS data written in
// PREVIOUS iterations (parity double-buffers for h1/xg; h2b is wave-private
// so same-wave program order via lgkmcnt is enough).
// fc head: wave2 drops h2 rows into a 128-slot ring; wave1 flushes 64
// outputs every 64 iters (ring distance 128 >> 64 => no overlap race).
__global__ __launch_bounds__(192, 1)
void gru_fused(const float* __restrict__ x,
               const float* __restrict__ Wih0, const float* __restrict__ Whh0,
               const float* __restrict__ bih0, const float* __restrict__ bhh0,
               const float* __restrict__ Wih1, const float* __restrict__ Whh1,
               const float* __restrict__ bih1, const float* __restrict__ bhh1,
               const float* __restrict__ fcw, const float* __restrict__ fcb,
               float* __restrict__ out)
{
    const int t  = threadIdx.x;
    const int wv = t >> 6;          // wave id 0..2
    const int j  = t & 63;          // lane
    const int b  = blockIdx.x;

    __shared__ __align__(16) float xs[TT * 2];        // 16 KB input
    __shared__ __align__(16) float h1b[2][HH];        // parity buffers
    __shared__ __align__(16) float h2b[HH];           // wave2-private
    __shared__ __align__(16) float xgb[2][3 * HH];    // parity buffers
    __shared__ __align__(16) float fwS[HH];
    __shared__ float ring[128][65];                   // h2 history, stride 65

    // ---- this wave's 3 rows of its recurrent matrix -> 48 float4 regs ----
    const float* Wm = (wv == 0) ? Whh0 : (wv == 1) ? Wih1 : Whh1;
    float4 w[48];
    #pragma unroll
    for (int r = 0; r < 3; ++r) {
        const float4* p = (const float4*)(Wm + (r * HH + j) * HH);
        #pragma unroll
        for (int k = 0; k < 16; ++k) w[r * 16 + k] = p[k];
    }
    // dot-phase biases (bhh0 / bih1 / bhh1 rows j, 64+j, 128+j)
    float ba, bbv, bc;
    if (wv == 0)      { ba = bhh0[j]; bbv = bhh0[HH + j]; bc = bhh0[2*HH + j]; }
    else if (wv == 1) { ba = bih1[j]; bbv = bih1[HH + j]; bc = bih1[2*HH + j]; }
    else              { ba = bhh1[j]; bbv = bhh1[HH + j]; bc = bhh1[2*HH + j]; }
    // wave0 input-side constants
    float wi0=0, wi1=0, wi2=0, wi3=0, wi4=0, wi5=0, bi0=0, bi1=0, bi2=0;
    if (wv == 0) {
        wi0 = Wih0[j*2];          wi1 = Wih0[j*2 + 1];
        wi2 = Wih0[(HH+j)*2];     wi3 = Wih0[(HH+j)*2 + 1];
        wi4 = Wih0[(2*HH+j)*2];   wi5 = Wih0[(2*HH+j)*2 + 1];
        bi0 = bih0[j]; bi1 = bih0[HH + j]; bi2 = bih0[2*HH + j];
    }
    const float fcbv = fcb[0];

    // ---- preload x, zero state ----
    {
        const float4* xp  = (const float4*)(x + (size_t)b * TT * 2);
        float4*       xsp = (float4*)xs;
        for (int i = t; i < TT * 2 / 4; i += 192) xsp[i] = xp[i];
    }
    if (t < HH) { h1b[0][t] = 0.f; h1b[1][t] = 0.f; h2b[t] = 0.f; fwS[t] = fcw[t]; }
    xgb[0][t] = 0.f; xgb[1][t] = 0.f;

    float hown = 0.f;   // wave0: h1[j];  wave2: h2[j]  (register-resident)

    for (int i = 0; i < TT + 2; ++i) {
        __syncthreads();
        const bool act = (wv == 0) ? (i < TT)
                       : (wv == 1) ? (i >= 1 && i < TT + 1)
                                   : (i >= 2);
        if (act) {
            // early reads (stable data from previous iterations)
            float x0 = 0.f, x1 = 0.f, g0 = 0.f, g1 = 0.f, g2 = 0.f;
            if (wv == 0) { x0 = xs[2*i]; x1 = xs[2*i + 1]; }
            if (wv == 2) {
                const float* xg = xgb[(i - 2) & 1];
                g0 = xg[j]; g1 = xg[HH + j]; g2 = xg[2*HH + j];
            }
            const float4* hb = (wv == 2) ? (const float4*)h2b
                                         : (const float4*)h1b[(i - 1) & 1];
            float a0 = ba, a1 = 0.f, b0 = bbv, b1 = 0.f, c0 = bc, c1 = 0.f;
            #pragma unroll
            for (int k = 0; k < 16; k += 2) {
                float4 hA = hb[k], hB = hb[k + 1];
                a0 += w[k   ].x*hA.x + w[k   ].y*hA.y + w[k   ].z*hA.z + w[k   ].w*hA.w;
                a1 += w[k+1 ].x*hB.x + w[k+1 ].y*hB.y + w[k+1 ].z*hB.z + w[k+1 ].w*hB.w;
                b0 += w[16+k].x*hA.x + w[16+k].y*hA.y + w[16+k].z*hA.z + w[16+k].w*hA.w;
                b1 += w[17+k].x*hB.x + w[17+k].y*hB.y + w[17+k].z*hB.z + w[17+k].w*hB.w;
                c0 += w[32+k].x*hA.x + w[32+k].y*hA.y + w[32+k].z*hA.z + w[32+k].w*hA.w;
                c1 += w[33+k].x*hB.x + w[33+k].y*hB.y + w[33+k].z*hB.z + w[33+k].w*hB.w;
            }
            const float A = a0 + a1, Bv = b0 + b1, C = c0 + c1;

            if (wv == 0) {                       // layer-1 gates, step i
                float r = sigm (wi0*x0 + wi1*x1 + bi0 + A);
                float z = sigm (wi2*x0 + wi3*x1 + bi1 + Bv);
                float n = ftanh(wi4*x0 + wi5*x1 + bi2 + r * C);
                hown = (1.f - z) * n + z * hown;
                h1b[i & 1][j] = hown;
            } else if (wv == 1) {                // xg for step i-1
                float* xg = xgb[(i - 1) & 1];
                xg[j] = A; xg[HH + j] = Bv; xg[2*HH + j] = C;
            } else {                             // layer-2 gates, step i-2
                float r = sigm (g0 + A);
                float z = sigm (g1 + Bv);
                float n = ftanh(g2 + r * C);
                hown = (1.f - z) * n + z * hown;
                h2b[j] = hown;
                ring[(i - 2) & 127][j] = hown;
            }
        }
        // fc-head flush: wave1, every 64 iters, 64 finished timesteps
        if (wv == 1 && i >= 66 && ((i - 66) & 63) == 0) {
            const int tt = ((i - 66) >> 6) * 64 + j;     // chunk c, lane j
            const float* rr = ring[tt & 127];
            float acc0 = 0.f, acc1 = 0.f;
            #pragma unroll
            for (int k = 0; k < 64; k += 2) {
                acc0 += rr[k]     * fwS[k];
                acc1 += rr[k + 1] * fwS[k + 1];
            }
            out[(size_t)b * TT + tt] = acc0 + acc1 + fcbv;
        }
    }
    __syncthreads();
    if (wv == 1) {                                // final chunk: t = 1984..2047
        const int tt = 31 * 64 + j;
        const float* rr = ring[tt & 127];
        float acc0 = 0.f, acc1 = 0.f;
        #pragma unroll
        for (int k = 0; k < 64; k += 2) {
            acc0 += rr[k]     * fwS[k];
            acc1 += rr[k + 1] * fwS[k + 1];
        }
        out[(size_t)b * TT + tt] = acc0 + acc1 + fcbv;
    }
}

extern "C" void kernel_launch(void* const* d_in, const int* in_sizes, int n_in,
                              void* d_out, int out_size, void* d_ws, size_t ws_size,
                              hipStream_t stream) {
    const float* x    = (const float*)d_in[0];
    const float* Wih0 = (const float*)d_in[1];
    const float* Whh0 = (const float*)d_in[2];
    const float* bih0 = (const float*)d_in[3];
    const float* bhh0 = (const float*)d_in[4];
    const float* Wih1 = (const float*)d_in[5];
    const float* Whh1 = (const float*)d_in[6];
    const float* bih1 = (const float*)d_in[7];
    const float* bhh1 = (const float*)d_in[8];
    const float* fcw  = (const float*)d_in[9];
    const float* fcb  = (const float*)d_in[10];
    float* out = (float*)d_out;

    gru_fused<<<BB, 192, 0, stream>>>(x, Wih0, Whh0, bih0, bhh0,
                                      Wih1, Whh1, bih1, bhh1, fcw, fcb, out);
}